// Round 1
// baseline (1853.079 us; speedup 1.0000x reference)
//
#include <hip/hip_runtime.h>
#include <cstdint>
#include <cstddef>

#define DNODE 64
#define HDIM 256
#define NLAYERS 3

// ---------------------------------------------------------------------------
// CSR build: deg histogram -> exclusive scan -> fill col by atomic cursor
// ---------------------------------------------------------------------------

__global__ __launch_bounds__(256) void k_deg(const int* __restrict__ dst, int* __restrict__ deg, int E) {
    int e = blockIdx.x * 256 + threadIdx.x;
    if (e < E) atomicAdd(&deg[dst[e]], 1);
}

__global__ __launch_bounds__(256) void k_scan_partial(const int* __restrict__ deg, int* __restrict__ bsum, int n) {
    __shared__ int sd[256];
    int tid = threadIdx.x;
    int base = blockIdx.x * 2048 + tid * 8;
    int s = 0;
#pragma unroll
    for (int j = 0; j < 8; j++) {
        int idx = base + j;
        if (idx < n) s += deg[idx];
    }
    sd[tid] = s;
    __syncthreads();
    for (int off = 128; off > 0; off >>= 1) {
        if (tid < off) sd[tid] += sd[tid + off];
        __syncthreads();
    }
    if (tid == 0) bsum[blockIdx.x] = sd[0];
}

__global__ void k_scan_bsum(int* bsum, int nb) {
    if (threadIdx.x == 0 && blockIdx.x == 0) {
        int run = 0;
        for (int i = 0; i < nb; i++) { int v = bsum[i]; bsum[i] = run; run += v; }
    }
}

__global__ __launch_bounds__(256) void k_scan_final(const int* __restrict__ deg, const int* __restrict__ bsum,
                                                    int* __restrict__ row_ptr, int* __restrict__ cursor,
                                                    float* __restrict__ inv_den, int n, int Etot) {
    __shared__ int tsum[256];
    int tid = threadIdx.x;
    int base = blockIdx.x * 2048 + tid * 8;
    int loc[8], dv[8];
    int s = 0;
#pragma unroll
    for (int j = 0; j < 8; j++) {
        int idx = base + j;
        int v = (idx < n) ? deg[idx] : 0;
        dv[j] = v;
        loc[j] = s;
        s += v;
    }
    tsum[tid] = s;
    __syncthreads();
    // Hillis-Steele inclusive scan of per-thread sums
    for (int off = 1; off < 256; off <<= 1) {
        int t = (tid >= off) ? tsum[tid - off] : 0;
        __syncthreads();
        tsum[tid] += t;
        __syncthreads();
    }
    int off0 = bsum[blockIdx.x] + (tid ? tsum[tid - 1] : 0);
#pragma unroll
    for (int j = 0; j < 8; j++) {
        int idx = base + j;
        if (idx < n) {
            int rp = off0 + loc[j];
            row_ptr[idx] = rp;
            cursor[idx] = rp;
            int d = dv[j];
            inv_den[idx] = 1.0f / (float)(d > 0 ? d : 1);
        }
    }
    if (blockIdx.x == 0 && tid == 0) row_ptr[n] = Etot;
}

__global__ __launch_bounds__(256) void k_fill(const int* __restrict__ src, const int* __restrict__ dst,
                                              int* __restrict__ cursor, int* __restrict__ col, int E) {
    int e = blockIdx.x * 256 + threadIdx.x;
    if (e < E) {
        int p = atomicAdd(&cursor[dst[e]], 1);
        col[p] = src[e];
    }
}

// ---------------------------------------------------------------------------
// Aggregation: msg[i,:] = inv_den[i] * sum_{j in CSR row i} h[col[j], :]
// One block per node; thread = feature column -> coalesced 1KB-row reads.
// ---------------------------------------------------------------------------
__global__ __launch_bounds__(256) void k_aggregate(const float* __restrict__ h, const int* __restrict__ row_ptr,
                                                   const int* __restrict__ col, const float* __restrict__ inv_den,
                                                   float* __restrict__ msg) {
    int node = blockIdx.x;
    int f = threadIdx.x;
    int s = row_ptr[node], e = row_ptr[node + 1];
    float acc = 0.f;
    for (int j = s; j < e; j++) {
        int c = col[j];
        acc += h[(size_t)c * HDIM + f];
    }
    msg[(size_t)node * HDIM + f] = acc * inv_den[node];
}

// ---------------------------------------------------------------------------
// fp32 GEMM: Cout[M,NN] = act( (ADD ? Cadd : 0) + A[M,K] @ B[K,NN] + bias )
// BM=BN=64, BK=16, 256 threads, 4x4 register tile per thread.
// In-place safe for Cadd==Cout (each elem read+written by owning thread only).
// ---------------------------------------------------------------------------
template <bool ADD, bool RELU>
__global__ __launch_bounds__(256) void k_gemm(const float* __restrict__ A, int K,
                                              const float* __restrict__ B,
                                              const float* __restrict__ bias,
                                              const float* __restrict__ Cadd,
                                              float* __restrict__ Cout,
                                              int M, int NN) {
    __shared__ float As[16][68];  // [k][m] transposed A tile
    __shared__ float Bs[16][68];  // [k][n]
    int tid = threadIdx.x;
    int tx = tid & 15, ty = tid >> 4;
    int row0 = blockIdx.y * 64;
    int col0 = blockIdx.x * 64;
    float acc[4][4] = {};

    int am = tid >> 2;            // 0..63 (A tile row)
    int ak = (tid & 3) << 2;      // 0,4,8,12 (A tile k base)
    int bn = (tid & 15) << 2;     // 0..60 (B tile col base)
    int bk = tid >> 4;            // 0..15 (B tile k)

    for (int k0 = 0; k0 < K; k0 += 16) {
        float4 av = make_float4(0.f, 0.f, 0.f, 0.f);
        int gr = row0 + am;
        if (gr < M) av = *(const float4*)&A[(size_t)gr * K + k0 + ak];
        As[ak + 0][am] = av.x;
        As[ak + 1][am] = av.y;
        As[ak + 2][am] = av.z;
        As[ak + 3][am] = av.w;
        float4 bv = *(const float4*)&B[(size_t)(k0 + bk) * NN + col0 + bn];
        *(float4*)&Bs[bk][bn] = bv;
        __syncthreads();
#pragma unroll
        for (int k = 0; k < 16; k++) {
            float4 a = *(const float4*)&As[k][ty << 2];
            float4 b = *(const float4*)&Bs[k][tx << 2];
            float ar[4] = {a.x, a.y, a.z, a.w};
            float br[4] = {b.x, b.y, b.z, b.w};
#pragma unroll
            for (int r = 0; r < 4; r++)
#pragma unroll
                for (int c = 0; c < 4; c++)
                    acc[r][c] = fmaf(ar[r], br[c], acc[r][c]);
        }
        __syncthreads();
    }

    int gc0 = col0 + (tx << 2);
    float4 bb = *(const float4*)&bias[gc0];
#pragma unroll
    for (int r = 0; r < 4; r++) {
        int gr = row0 + (ty << 2) + r;
        if (gr >= M) continue;
        float4 v = make_float4(acc[r][0] + bb.x, acc[r][1] + bb.y, acc[r][2] + bb.z, acc[r][3] + bb.w);
        if (ADD) {
            float4 cv = *(const float4*)&Cadd[(size_t)gr * NN + gc0];
            v.x += cv.x; v.y += cv.y; v.z += cv.z; v.w += cv.w;
        }
        if (RELU) {
            v.x = fmaxf(v.x, 0.f); v.y = fmaxf(v.y, 0.f);
            v.z = fmaxf(v.z, 0.f); v.w = fmaxf(v.w, 0.f);
        }
        *(float4*)&Cout[(size_t)gr * NN + gc0] = v;
    }
}

// ---------------------------------------------------------------------------
// Column sum (for mean) + tiny MLP head
// ---------------------------------------------------------------------------
__global__ __launch_bounds__(256) void k_colsum(const float* __restrict__ h, float* __restrict__ g, int n) {
    int f = threadIdx.x;
    float acc = 0.f;
    for (int i = blockIdx.x; i < n; i += gridDim.x) acc += h[(size_t)i * HDIM + f];
    atomicAdd(&g[f], acc);
}

__global__ __launch_bounds__(256) void k_mlp(const float* __restrict__ g, const float* __restrict__ w1,
                                             const float* __restrict__ b1, const float* __restrict__ w2,
                                             const float* __restrict__ b2, float* __restrict__ out, float invN) {
    __shared__ float gs[256];
    __shared__ float ts[256];
    int f = threadIdx.x;
    gs[f] = g[f] * invN;
    __syncthreads();
    float a = b1[f];
    for (int k = 0; k < 256; k++) a = fmaf(gs[k], w1[k * 256 + f], a);
    ts[f] = fmaxf(a, 0.f);
    __syncthreads();
    float o = b2[f];
    for (int k = 0; k < 256; k++) o = fmaf(ts[k], w2[k * 256 + f], o);
    out[f] = o;
}

// ---------------------------------------------------------------------------
extern "C" void kernel_launch(void* const* d_in, const int* in_sizes, int n_in,
                              void* d_out, int out_size, void* d_ws, size_t ws_size,
                              hipStream_t stream) {
    const float* x      = (const float*)d_in[0];
    const int*   src    = (const int*)d_in[1];
    const int*   dst    = (const int*)d_in[2];
    const float* w_node = (const float*)d_in[3];
    const float* b_node = (const float*)d_in[4];
    const float* w_gnn  = (const float*)d_in[5];
    const float* b_gnn  = (const float*)d_in[6];
    const float* w_p1   = (const float*)d_in[7];
    const float* b_p1   = (const float*)d_in[8];
    const float* w_p2   = (const float*)d_in[9];
    const float* b_p2   = (const float*)d_in[10];
    float* out = (float*)d_out;

    const int N = in_sizes[0] / DNODE;  // 100000
    const int E = in_sizes[1];          // 1600000

    // workspace layout (~213 MB)
    char* w = (char*)d_ws;
    float* h       = (float*)w; w += (size_t)N * HDIM * 4;
    float* msg     = (float*)w; w += (size_t)N * HDIM * 4;
    int*   deg     = (int*)w;   w += (size_t)N * 4;
    int*   row_ptr = (int*)w;   w += (size_t)(N + 1) * 4;
    int*   cursor  = (int*)w;   w += (size_t)N * 4;
    int*   colx    = (int*)w;   w += (size_t)E * 4;
    float* inv_den = (float*)w; w += (size_t)N * 4;
    float* g       = (float*)w; w += 256 * 4;
    int*   bsum    = (int*)w;   w += 256 * 4;
    (void)ws_size; (void)n_in; (void)out_size;

    hipMemsetAsync(deg, 0, (size_t)N * 4, stream);
    hipMemsetAsync(g, 0, 256 * 4, stream);

    k_deg<<<(E + 255) / 256, 256, 0, stream>>>(dst, deg, E);
    int nb = (N + 2047) / 2048;
    k_scan_partial<<<nb, 256, 0, stream>>>(deg, bsum, N);
    k_scan_bsum<<<1, 64, 0, stream>>>(bsum, nb);
    k_scan_final<<<nb, 256, 0, stream>>>(deg, bsum, row_ptr, cursor, inv_den, N, E);
    k_fill<<<(E + 255) / 256, 256, 0, stream>>>(src, dst, cursor, colx, E);

    dim3 ggrid(HDIM / 64, (N + 63) / 64);
    // h = x @ w_node + b_node
    k_gemm<false, false><<<ggrid, 256, 0, stream>>>(x, DNODE, w_node, b_node, nullptr, h, N, HDIM);

    for (int l = 0; l < NLAYERS; l++) {
        k_aggregate<<<N, 256, 0, stream>>>(h, row_ptr, colx, inv_den, msg);
        // h = relu(h + msg @ w_gnn[l] + b_gnn[l])   (in-place)
        k_gemm<true, true><<<ggrid, 256, 0, stream>>>(msg, HDIM, w_gnn + (size_t)l * HDIM * HDIM,
                                                      b_gnn + (size_t)l * HDIM, h, h, N, HDIM);
    }

    k_colsum<<<512, 256, 0, stream>>>(h, g, N);
    k_mlp<<<1, 256, 0, stream>>>(g, w_p1, b_p1, w_p2, b_p2, out, 1.0f / (float)N);
}

// Round 2
// 1440.424 us; speedup vs baseline: 1.2865x; 1.2865x over previous
//
#include <hip/hip_runtime.h>
#include <hip/hip_bf16.h>
#include <cstdint>
#include <cstddef>

#define DNODE 64
#define HDIM 256
#define NLAYERS 3

// ---------------------------------------------------------------------------
// CSR build: deg histogram -> exclusive scan -> fill col by atomic cursor
// ---------------------------------------------------------------------------

__global__ __launch_bounds__(256) void k_deg(const int* __restrict__ dst, int* __restrict__ deg, int E) {
    int e = blockIdx.x * 256 + threadIdx.x;
    if (e < E) atomicAdd(&deg[dst[e]], 1);
}

__global__ __launch_bounds__(256) void k_scan_partial(const int* __restrict__ deg, int* __restrict__ bsum, int n) {
    __shared__ int sd[256];
    int tid = threadIdx.x;
    int base = blockIdx.x * 2048 + tid * 8;
    int s = 0;
#pragma unroll
    for (int j = 0; j < 8; j++) {
        int idx = base + j;
        if (idx < n) s += deg[idx];
    }
    sd[tid] = s;
    __syncthreads();
    for (int off = 128; off > 0; off >>= 1) {
        if (tid < off) sd[tid] += sd[tid + off];
        __syncthreads();
    }
    if (tid == 0) bsum[blockIdx.x] = sd[0];
}

__global__ void k_scan_bsum(int* bsum, int nb) {
    if (threadIdx.x == 0 && blockIdx.x == 0) {
        int run = 0;
        for (int i = 0; i < nb; i++) { int v = bsum[i]; bsum[i] = run; run += v; }
    }
}

__global__ __launch_bounds__(256) void k_scan_final(const int* __restrict__ deg, const int* __restrict__ bsum,
                                                    int* __restrict__ row_ptr, int* __restrict__ cursor,
                                                    float* __restrict__ inv_den, int n, int Etot) {
    __shared__ int tsum[256];
    int tid = threadIdx.x;
    int base = blockIdx.x * 2048 + tid * 8;
    int loc[8], dv[8];
    int s = 0;
#pragma unroll
    for (int j = 0; j < 8; j++) {
        int idx = base + j;
        int v = (idx < n) ? deg[idx] : 0;
        dv[j] = v;
        loc[j] = s;
        s += v;
    }
    tsum[tid] = s;
    __syncthreads();
    for (int off = 1; off < 256; off <<= 1) {
        int t = (tid >= off) ? tsum[tid - off] : 0;
        __syncthreads();
        tsum[tid] += t;
        __syncthreads();
    }
    int off0 = bsum[blockIdx.x] + (tid ? tsum[tid - 1] : 0);
#pragma unroll
    for (int j = 0; j < 8; j++) {
        int idx = base + j;
        if (idx < n) {
            int rp = off0 + loc[j];
            row_ptr[idx] = rp;
            cursor[idx] = rp;
            int d = dv[j];
            inv_den[idx] = 1.0f / (float)(d > 0 ? d : 1);
        }
    }
    if (blockIdx.x == 0 && tid == 0) row_ptr[n] = Etot;
}

__global__ __launch_bounds__(256) void k_fill(const int* __restrict__ src, const int* __restrict__ dst,
                                              int* __restrict__ cursor, int* __restrict__ col, int E) {
    int e = blockIdx.x * 256 + threadIdx.x;
    if (e < E) {
        int p = atomicAdd(&cursor[dst[e]], 1);
        col[p] = src[e];
    }
}

// ---------------------------------------------------------------------------
// Aggregation v2: one 64-lane wave per node, bf16 gather rows (512B/row),
// fp32 accumulate, fp32 msg write. Lane handles 4 features (ushort4 load).
// ---------------------------------------------------------------------------
__global__ __launch_bounds__(256) void k_aggregate_bf16(const ushort* __restrict__ hb,
                                                        const int* __restrict__ row_ptr,
                                                        const int* __restrict__ col,
                                                        const float* __restrict__ inv_den,
                                                        float* __restrict__ msg, int n) {
    int node = blockIdx.x * 4 + (threadIdx.x >> 6);
    if (node >= n) return;
    int lane = threadIdx.x & 63;
    int s = row_ptr[node], e = row_ptr[node + 1];
    float a0 = 0.f, a1 = 0.f, a2 = 0.f, a3 = 0.f;
    const ushort* hp = hb + (size_t)lane * 4;
    for (int j = s; j < e; j++) {
        int c = col[j];
        ushort4 v = *(const ushort4*)&hp[(size_t)c * HDIM];
        a0 += __uint_as_float((uint32_t)v.x << 16);
        a1 += __uint_as_float((uint32_t)v.y << 16);
        a2 += __uint_as_float((uint32_t)v.z << 16);
        a3 += __uint_as_float((uint32_t)v.w << 16);
    }
    float inv = inv_den[node];
    float4 o = make_float4(a0 * inv, a1 * inv, a2 * inv, a3 * inv);
    *(float4*)&msg[(size_t)node * HDIM + lane * 4] = o;
}

// Fallback (fp32 gather), used only if ws too small for the bf16 mirror.
__global__ __launch_bounds__(256) void k_aggregate(const float* __restrict__ h, const int* __restrict__ row_ptr,
                                                   const int* __restrict__ col, const float* __restrict__ inv_den,
                                                   float* __restrict__ msg) {
    int node = blockIdx.x;
    int f = threadIdx.x;
    int s = row_ptr[node], e = row_ptr[node + 1];
    float acc = 0.f;
    for (int j = s; j < e; j++) {
        int c = col[j];
        acc += h[(size_t)c * HDIM + f];
    }
    msg[(size_t)node * HDIM + f] = acc * inv_den[node];
}

// ---------------------------------------------------------------------------
// fp32 GEMM: Cout[M,NN] = act( (ADD ? Cadd : 0) + A[M,K] @ B[K,NN] + bias )
// BM=BN=64, BK=16, 256 threads, 4x4 register tile. Optional bf16 mirror write.
// ---------------------------------------------------------------------------
struct __align__(8) bf4 { ushort x, y, z, w; };

__device__ __forceinline__ ushort f2bf(float f) {
    __hip_bfloat16 b = __float2bfloat16(f);
    return *(ushort*)&b;
}

template <bool ADD, bool RELU, bool WBF>
__global__ __launch_bounds__(256) void k_gemm(const float* __restrict__ A, int K,
                                              const float* __restrict__ B,
                                              const float* __restrict__ bias,
                                              const float* __restrict__ Cadd,
                                              float* __restrict__ Cout,
                                              ushort* __restrict__ hb,
                                              int M, int NN) {
    __shared__ float As[16][68];  // [k][m]
    __shared__ float Bs[16][68];  // [k][n]
    int tid = threadIdx.x;
    int tx = tid & 15, ty = tid >> 4;
    int row0 = blockIdx.y * 64;
    int col0 = blockIdx.x * 64;
    float acc[4][4] = {};

    int am = tid >> 2;
    int ak = (tid & 3) << 2;
    int bn = (tid & 15) << 2;
    int bk = tid >> 4;

    for (int k0 = 0; k0 < K; k0 += 16) {
        float4 av = make_float4(0.f, 0.f, 0.f, 0.f);
        int gr = row0 + am;
        if (gr < M) av = *(const float4*)&A[(size_t)gr * K + k0 + ak];
        As[ak + 0][am] = av.x;
        As[ak + 1][am] = av.y;
        As[ak + 2][am] = av.z;
        As[ak + 3][am] = av.w;
        float4 bv = *(const float4*)&B[(size_t)(k0 + bk) * NN + col0 + bn];
        *(float4*)&Bs[bk][bn] = bv;
        __syncthreads();
#pragma unroll
        for (int k = 0; k < 16; k++) {
            float4 a = *(const float4*)&As[k][ty << 2];
            float4 b = *(const float4*)&Bs[k][tx << 2];
            float ar[4] = {a.x, a.y, a.z, a.w};
            float br[4] = {b.x, b.y, b.z, b.w};
#pragma unroll
            for (int r = 0; r < 4; r++)
#pragma unroll
                for (int c = 0; c < 4; c++)
                    acc[r][c] = fmaf(ar[r], br[c], acc[r][c]);
        }
        __syncthreads();
    }

    int gc0 = col0 + (tx << 2);
    float4 bb = *(const float4*)&bias[gc0];
#pragma unroll
    for (int r = 0; r < 4; r++) {
        int gr = row0 + (ty << 2) + r;
        if (gr >= M) continue;
        float4 v = make_float4(acc[r][0] + bb.x, acc[r][1] + bb.y, acc[r][2] + bb.z, acc[r][3] + bb.w);
        if (ADD) {
            float4 cv = *(const float4*)&Cadd[(size_t)gr * NN + gc0];
            v.x += cv.x; v.y += cv.y; v.z += cv.z; v.w += cv.w;
        }
        if (RELU) {
            v.x = fmaxf(v.x, 0.f); v.y = fmaxf(v.y, 0.f);
            v.z = fmaxf(v.z, 0.f); v.w = fmaxf(v.w, 0.f);
        }
        *(float4*)&Cout[(size_t)gr * NN + gc0] = v;
        if (WBF) {
            bf4 o;
            o.x = f2bf(v.x); o.y = f2bf(v.y); o.z = f2bf(v.z); o.w = f2bf(v.w);
            *(bf4*)&hb[(size_t)gr * NN + gc0] = o;
        }
    }
}

// ---------------------------------------------------------------------------
// Column sum (for mean) + tiny MLP head
// ---------------------------------------------------------------------------
__global__ __launch_bounds__(256) void k_colsum(const float* __restrict__ h, float* __restrict__ g, int n) {
    int f = threadIdx.x;
    float acc = 0.f;
    for (int i = blockIdx.x; i < n; i += gridDim.x) acc += h[(size_t)i * HDIM + f];
    atomicAdd(&g[f], acc);
}

__global__ __launch_bounds__(256) void k_mlp(const float* __restrict__ g, const float* __restrict__ w1,
                                             const float* __restrict__ b1, const float* __restrict__ w2,
                                             const float* __restrict__ b2, float* __restrict__ out, float invN) {
    __shared__ float gs[256];
    __shared__ float ts[256];
    int f = threadIdx.x;
    gs[f] = g[f] * invN;
    __syncthreads();
    float a = b1[f];
    for (int k = 0; k < 256; k++) a = fmaf(gs[k], w1[k * 256 + f], a);
    ts[f] = fmaxf(a, 0.f);
    __syncthreads();
    float o = b2[f];
    for (int k = 0; k < 256; k++) o = fmaf(ts[k], w2[k * 256 + f], o);
    out[f] = o;
}

// ---------------------------------------------------------------------------
extern "C" void kernel_launch(void* const* d_in, const int* in_sizes, int n_in,
                              void* d_out, int out_size, void* d_ws, size_t ws_size,
                              hipStream_t stream) {
    const float* x      = (const float*)d_in[0];
    const int*   src    = (const int*)d_in[1];
    const int*   dst    = (const int*)d_in[2];
    const float* w_node = (const float*)d_in[3];
    const float* b_node = (const float*)d_in[4];
    const float* w_gnn  = (const float*)d_in[5];
    const float* b_gnn  = (const float*)d_in[6];
    const float* w_p1   = (const float*)d_in[7];
    const float* b_p1   = (const float*)d_in[8];
    const float* w_p2   = (const float*)d_in[9];
    const float* b_p2   = (const float*)d_in[10];
    float* out = (float*)d_out;

    const int N = in_sizes[0] / DNODE;  // 100000
    const int E = in_sizes[1];          // 1600000

    // workspace layout
    char* w = (char*)d_ws;
    float* h       = (float*)w; w += (size_t)N * HDIM * 4;
    float* msg     = (float*)w; w += (size_t)N * HDIM * 4;
    int*   deg     = (int*)w;   w += (size_t)N * 4;
    int*   row_ptr = (int*)w;   w += (size_t)(N + 1) * 4;
    int*   cursor  = (int*)w;   w += (size_t)N * 4;
    int*   colx    = (int*)w;   w += (size_t)E * 4;
    float* inv_den = (float*)w; w += (size_t)N * 4;
    float* g       = (float*)w; w += 256 * 4;
    int*   bsum    = (int*)w;   w += 256 * 4;
    ushort* hb     = (ushort*)w; w += (size_t)N * HDIM * 2;
    bool use_bf16 = ((size_t)(w - (char*)d_ws) <= ws_size);
    (void)n_in; (void)out_size;

    hipMemsetAsync(deg, 0, (size_t)N * 4, stream);
    hipMemsetAsync(g, 0, 256 * 4, stream);

    k_deg<<<(E + 255) / 256, 256, 0, stream>>>(dst, deg, E);
    int nb = (N + 2047) / 2048;
    k_scan_partial<<<nb, 256, 0, stream>>>(deg, bsum, N);
    k_scan_bsum<<<1, 64, 0, stream>>>(bsum, nb);
    k_scan_final<<<nb, 256, 0, stream>>>(deg, bsum, row_ptr, cursor, inv_den, N, E);
    k_fill<<<(E + 255) / 256, 256, 0, stream>>>(src, dst, cursor, colx, E);

    dim3 ggrid(HDIM / 64, (N + 63) / 64);
    if (use_bf16) {
        // h = x @ w_node + b_node  (+ bf16 mirror)
        k_gemm<false, false, true><<<ggrid, 256, 0, stream>>>(x, DNODE, w_node, b_node, nullptr, h, hb, N, HDIM);
        for (int l = 0; l < NLAYERS; l++) {
            k_aggregate_bf16<<<(N + 3) / 4, 256, 0, stream>>>(hb, row_ptr, colx, inv_den, msg, N);
            const float* wg = w_gnn + (size_t)l * HDIM * HDIM;
            const float* bg = b_gnn + (size_t)l * HDIM;
            if (l < NLAYERS - 1)
                k_gemm<true, true, true><<<ggrid, 256, 0, stream>>>(msg, HDIM, wg, bg, h, h, hb, N, HDIM);
            else
                k_gemm<true, true, false><<<ggrid, 256, 0, stream>>>(msg, HDIM, wg, bg, h, h, nullptr, N, HDIM);
        }
    } else {
        k_gemm<false, false, false><<<ggrid, 256, 0, stream>>>(x, DNODE, w_node, b_node, nullptr, h, nullptr, N, HDIM);
        for (int l = 0; l < NLAYERS; l++) {
            k_aggregate<<<N, 256, 0, stream>>>(h, row_ptr, colx, inv_den, msg);
            k_gemm<true, true, false><<<ggrid, 256, 0, stream>>>(msg, HDIM, w_gnn + (size_t)l * HDIM * HDIM,
                                                                 b_gnn + (size_t)l * HDIM, h, h, nullptr, N, HDIM);
        }
    }

    k_colsum<<<512, 256, 0, stream>>>(h, g, N);
    k_mlp<<<1, 256, 0, stream>>>(g, w_p1, b_p1, w_p2, b_p2, out, 1.0f / (float)N);
}

// Round 3
// 1003.441 us; speedup vs baseline: 1.8467x; 1.4355x over previous
//
#include <hip/hip_runtime.h>
#include <hip/hip_bf16.h>
#include <cstdint>
#include <cstddef>

#define DNODE 64
#define HDIM 256
#define NLAYERS 3

typedef __attribute__((ext_vector_type(8))) short bf16x8;
typedef __attribute__((ext_vector_type(4))) float f32x4;

__device__ __forceinline__ ushort f2bf(float f) {
    __hip_bfloat16 b = __float2bfloat16(f);
    return *(ushort*)&b;
}
__device__ __forceinline__ float bf2f(ushort u) {
    return __uint_as_float((uint32_t)u << 16);
}

// ---------------------------------------------------------------------------
// CSR build: deg histogram -> exclusive scan -> fill col by atomic cursor
// ---------------------------------------------------------------------------

__global__ __launch_bounds__(256) void k_deg(const int* __restrict__ dst, int* __restrict__ deg, int E) {
    int e = blockIdx.x * 256 + threadIdx.x;
    if (e < E) atomicAdd(&deg[dst[e]], 1);
}

__global__ __launch_bounds__(256) void k_scan_partial(const int* __restrict__ deg, int* __restrict__ bsum, int n) {
    __shared__ int sd[256];
    int tid = threadIdx.x;
    int base = blockIdx.x * 2048 + tid * 8;
    int s = 0;
#pragma unroll
    for (int j = 0; j < 8; j++) {
        int idx = base + j;
        if (idx < n) s += deg[idx];
    }
    sd[tid] = s;
    __syncthreads();
    for (int off = 128; off > 0; off >>= 1) {
        if (tid < off) sd[tid] += sd[tid + off];
        __syncthreads();
    }
    if (tid == 0) bsum[blockIdx.x] = sd[0];
}

__global__ void k_scan_bsum(int* bsum, int nb) {
    if (threadIdx.x == 0 && blockIdx.x == 0) {
        int run = 0;
        for (int i = 0; i < nb; i++) { int v = bsum[i]; bsum[i] = run; run += v; }
    }
}

__global__ __launch_bounds__(256) void k_scan_final(const int* __restrict__ deg, const int* __restrict__ bsum,
                                                    int* __restrict__ row_ptr, int* __restrict__ cursor,
                                                    float* __restrict__ inv_den, int n, int Etot) {
    __shared__ int tsum[256];
    int tid = threadIdx.x;
    int base = blockIdx.x * 2048 + tid * 8;
    int loc[8], dv[8];
    int s = 0;
#pragma unroll
    for (int j = 0; j < 8; j++) {
        int idx = base + j;
        int v = (idx < n) ? deg[idx] : 0;
        dv[j] = v;
        loc[j] = s;
        s += v;
    }
    tsum[tid] = s;
    __syncthreads();
    for (int off = 1; off < 256; off <<= 1) {
        int t = (tid >= off) ? tsum[tid - off] : 0;
        __syncthreads();
        tsum[tid] += t;
        __syncthreads();
    }
    int off0 = bsum[blockIdx.x] + (tid ? tsum[tid - 1] : 0);
#pragma unroll
    for (int j = 0; j < 8; j++) {
        int idx = base + j;
        if (idx < n) {
            int rp = off0 + loc[j];
            row_ptr[idx] = rp;
            cursor[idx] = rp;
            int d = dv[j];
            inv_den[idx] = 1.0f / (float)(d > 0 ? d : 1);
        }
    }
    if (blockIdx.x == 0 && tid == 0) row_ptr[n] = Etot;
}

__global__ __launch_bounds__(256) void k_fill(const int* __restrict__ src, const int* __restrict__ dst,
                                              int* __restrict__ cursor, int* __restrict__ col, int E) {
    int e = blockIdx.x * 256 + threadIdx.x;
    if (e < E) {
        int p = atomicAdd(&cursor[dst[e]], 1);
        col[p] = src[e];
    }
}

// ---------------------------------------------------------------------------
// Converters: x -> bf16;  W[K][256] fp32 -> Wt[256][K] bf16 (B^T for MFMA)
// ---------------------------------------------------------------------------
__global__ __launch_bounds__(256) void k_xconv(const float* __restrict__ x, ushort* __restrict__ xb, int n4) {
    int i = blockIdx.x * 256 + threadIdx.x;
    if (i >= n4) return;
    float4 v = *(const float4*)&x[(size_t)i * 4];
    ushort4 o;
    o.x = f2bf(v.x); o.y = f2bf(v.y); o.z = f2bf(v.z); o.w = f2bf(v.w);
    *(ushort4*)&xb[(size_t)i * 4] = o;
}

__global__ __launch_bounds__(256) void k_wconv(const float* __restrict__ src, ushort* __restrict__ dst, int K) {
    int n = threadIdx.x;             // output row (0..255)
    int k0 = blockIdx.x * 16;
#pragma unroll
    for (int i = 0; i < 16; i++) {
        int k = k0 + i;
        dst[(size_t)n * K + k] = f2bf(src[(size_t)k * 256 + n]);
    }
}

// ---------------------------------------------------------------------------
// Aggregation: one wave per node, bf16 gather rows (512B), fp32 acc, bf16 out
// ---------------------------------------------------------------------------
__global__ __launch_bounds__(256) void k_aggregate_bf16(const ushort* __restrict__ hb,
                                                        const int* __restrict__ row_ptr,
                                                        const int* __restrict__ col,
                                                        const float* __restrict__ inv_den,
                                                        ushort* __restrict__ msgb, int n) {
    int node = blockIdx.x * 4 + (threadIdx.x >> 6);
    if (node >= n) return;
    int lane = threadIdx.x & 63;
    int s = row_ptr[node], e = row_ptr[node + 1];
    float a0 = 0.f, a1 = 0.f, a2 = 0.f, a3 = 0.f;
    const ushort* hp = hb + (size_t)lane * 4;
    for (int j = s; j < e; j++) {
        int c = col[j];
        ushort4 v = *(const ushort4*)&hp[(size_t)c * HDIM];
        a0 += bf2f(v.x);
        a1 += bf2f(v.y);
        a2 += bf2f(v.z);
        a3 += bf2f(v.w);
    }
    float inv = inv_den[node];
    ushort4 o;
    o.x = f2bf(a0 * inv); o.y = f2bf(a1 * inv); o.z = f2bf(a2 * inv); o.w = f2bf(a3 * inv);
    *(ushort4*)&msgb[(size_t)node * HDIM + lane * 4] = o;
}

// ---------------------------------------------------------------------------
// bf16 MFMA GEMM: H[M][256] = act( (ADD?H:0) + A[M][K] @ Bt[256][K]^T + bias )
// 64x64 tile, 4 waves, 16x16x32 MFMA, fp32 accum. In-place safe on H.
// ---------------------------------------------------------------------------
template <bool ADD, bool RELU>
__global__ __launch_bounds__(256) void k_gemm_mfma(const ushort* __restrict__ A,
                                                   const ushort* __restrict__ Bt,
                                                   const float* __restrict__ bias,
                                                   ushort* __restrict__ H,
                                                   int M, int K) {
    __shared__ ushort As[64][40];  // pad to 80B rows
    __shared__ ushort Bs[64][40];
    int tid = threadIdx.x;
    int w = tid >> 6, l = tid & 63;
    int row0 = blockIdx.y * 64, col0 = blockIdx.x * 64;
    int sr = tid >> 2, sc = (tid & 3) * 8;   // staging coords
    int wm = (w >> 1) * 32, wn = (w & 1) * 32;
    int fr = l & 15, fk = (l >> 4) * 8;
    f32x4 acc[2][2] = {};

    for (int k0 = 0; k0 < K; k0 += 32) {
        bf16x8 av = {0, 0, 0, 0, 0, 0, 0, 0};
        int gr = row0 + sr;
        if (gr < M) av = *(const bf16x8*)&A[(size_t)gr * K + k0 + sc];
        *(bf16x8*)&As[sr][sc] = av;
        bf16x8 bv = *(const bf16x8*)&Bt[(size_t)(col0 + sr) * K + k0 + sc];
        *(bf16x8*)&Bs[sr][sc] = bv;
        __syncthreads();
        bf16x8 af[2], bf[2];
#pragma unroll
        for (int mi = 0; mi < 2; mi++) af[mi] = *(const bf16x8*)&As[wm + mi * 16 + fr][fk];
#pragma unroll
        for (int ni = 0; ni < 2; ni++) bf[ni] = *(const bf16x8*)&Bs[wn + ni * 16 + fr][fk];
#pragma unroll
        for (int mi = 0; mi < 2; mi++)
#pragma unroll
            for (int ni = 0; ni < 2; ni++)
                acc[mi][ni] = __builtin_amdgcn_mfma_f32_16x16x32_bf16(af[mi], bf[ni], acc[mi][ni], 0, 0, 0);
        __syncthreads();
    }

#pragma unroll
    for (int ni = 0; ni < 2; ni++) {
        int gcol = col0 + wn + ni * 16 + fr;
        float bb = bias[gcol];
#pragma unroll
        for (int mi = 0; mi < 2; mi++) {
#pragma unroll
            for (int j = 0; j < 4; j++) {
                int grow = row0 + wm + mi * 16 + (l >> 4) * 4 + j;
                if (grow >= M) continue;
                size_t idx = (size_t)grow * HDIM + gcol;
                float v = acc[mi][ni][j] + bb;
                if (ADD) v += bf2f(H[idx]);
                if (RELU) v = fmaxf(v, 0.f);
                H[idx] = f2bf(v);
            }
        }
    }
}

// ---------------------------------------------------------------------------
// Column sum (bf16 in, fp32 atomics) + tiny MLP head (fp32)
// ---------------------------------------------------------------------------
__global__ __launch_bounds__(256) void k_colsum_bf(const ushort* __restrict__ hb, float* __restrict__ g, int n) {
    int f = threadIdx.x;
    float acc = 0.f;
    for (int i = blockIdx.x; i < n; i += gridDim.x) acc += bf2f(hb[(size_t)i * HDIM + f]);
    atomicAdd(&g[f], acc);
}

__global__ __launch_bounds__(256) void k_mlp(const float* __restrict__ g, const float* __restrict__ w1,
                                             const float* __restrict__ b1, const float* __restrict__ w2,
                                             const float* __restrict__ b2, float* __restrict__ out, float invN) {
    __shared__ float gs[256];
    __shared__ float ts[256];
    int f = threadIdx.x;
    gs[f] = g[f] * invN;
    __syncthreads();
    float a = b1[f];
    for (int k = 0; k < 256; k++) a = fmaf(gs[k], w1[k * 256 + f], a);
    ts[f] = fmaxf(a, 0.f);
    __syncthreads();
    float o = b2[f];
    for (int k = 0; k < 256; k++) o = fmaf(ts[k], w2[k * 256 + f], o);
    out[f] = o;
}

// ---------------------------------------------------------------------------
extern "C" void kernel_launch(void* const* d_in, const int* in_sizes, int n_in,
                              void* d_out, int out_size, void* d_ws, size_t ws_size,
                              hipStream_t stream) {
    const float* x      = (const float*)d_in[0];
    const int*   src    = (const int*)d_in[1];
    const int*   dst    = (const int*)d_in[2];
    const float* w_node = (const float*)d_in[3];
    const float* b_node = (const float*)d_in[4];
    const float* w_gnn  = (const float*)d_in[5];
    const float* b_gnn  = (const float*)d_in[6];
    const float* w_p1   = (const float*)d_in[7];
    const float* b_p1   = (const float*)d_in[8];
    const float* w_p2   = (const float*)d_in[9];
    const float* b_p2   = (const float*)d_in[10];
    float* out = (float*)d_out;

    const int N = in_sizes[0] / DNODE;  // 100000
    const int E = in_sizes[1];          // 1600000

    // workspace layout (~125 MB)
    char* w = (char*)d_ws;
    ushort* hb     = (ushort*)w; w += (size_t)N * HDIM * 2;
    ushort* msgb   = (ushort*)w; w += (size_t)N * HDIM * 2;
    ushort* xb     = (ushort*)w; w += (size_t)N * DNODE * 2;
    ushort* wnt    = (ushort*)w; w += (size_t)HDIM * DNODE * 2;            // [256][64]
    ushort* wgt    = (ushort*)w; w += (size_t)NLAYERS * HDIM * HDIM * 2;   // [l][256][256]
    int*   deg     = (int*)w;   w += (size_t)N * 4;
    int*   row_ptr = (int*)w;   w += (size_t)(N + 1) * 4;
    int*   cursor  = (int*)w;   w += (size_t)N * 4;
    int*   colx    = (int*)w;   w += (size_t)E * 4;
    float* inv_den = (float*)w; w += (size_t)N * 4;
    float* g       = (float*)w; w += 256 * 4;
    int*   bsum    = (int*)w;   w += 256 * 4;
    (void)ws_size; (void)n_in; (void)out_size;

    hipMemsetAsync(deg, 0, (size_t)N * 4, stream);
    hipMemsetAsync(g, 0, 256 * 4, stream);

    // CSR build
    k_deg<<<(E + 255) / 256, 256, 0, stream>>>(dst, deg, E);
    int nb = (N + 2047) / 2048;
    k_scan_partial<<<nb, 256, 0, stream>>>(deg, bsum, N);
    k_scan_bsum<<<1, 64, 0, stream>>>(bsum, nb);
    k_scan_final<<<nb, 256, 0, stream>>>(deg, bsum, row_ptr, cursor, inv_den, N, E);
    k_fill<<<(E + 255) / 256, 256, 0, stream>>>(src, dst, cursor, colx, E);

    // converts
    k_xconv<<<(N * DNODE / 4 + 255) / 256, 256, 0, stream>>>(x, xb, N * DNODE / 4);
    k_wconv<<<DNODE / 16, 256, 0, stream>>>(w_node, wnt, DNODE);
    for (int l = 0; l < NLAYERS; l++)
        k_wconv<<<HDIM / 16, 256, 0, stream>>>(w_gnn + (size_t)l * HDIM * HDIM,
                                               wgt + (size_t)l * HDIM * HDIM, HDIM);

    dim3 gg(HDIM / 64, (N + 63) / 64);
    // h = x @ w_node + b_node
    k_gemm_mfma<false, false><<<gg, 256, 0, stream>>>(xb, wnt, b_node, hb, N, DNODE);

    for (int l = 0; l < NLAYERS; l++) {
        k_aggregate_bf16<<<(N + 3) / 4, 256, 0, stream>>>(hb, row_ptr, colx, inv_den, msgb, N);
        // h = relu(h + msg @ w_gnn[l] + b_gnn[l])   (in-place on hb)
        k_gemm_mfma<true, true><<<gg, 256, 0, stream>>>(msgb, wgt + (size_t)l * HDIM * HDIM,
                                                        b_gnn + (size_t)l * HDIM, hb, N, HDIM);
    }

    k_colsum_bf<<<512, 256, 0, stream>>>(hb, g, N);
    k_mlp<<<1, 256, 0, stream>>>(g, w_p1, b_p1, w_p2, b_p2, out, 1.0f / (float)N);
}